// Round 7
// baseline (235.446 us; speedup 1.0000x reference)
//
#include <hip/hip_runtime.h>

#define B_G   100
#define N_PER 1000
#define E_PER 12000
#define NTOT  (B_G * N_PER)
#define ETOT  (B_G * E_PER)
#define KSEL  800
#define EPT   12

typedef __attribute__((ext_vector_type(8))) short short8;
typedef __attribute__((ext_vector_type(4))) float float4_;

__device__ __forceinline__ unsigned short f2bf(float f) {
    unsigned u = __float_as_uint(f);
    u += 0x7fffu + ((u >> 16) & 1u);          // RNE
    return (unsigned short)(u >> 16);
}
__device__ __forceinline__ float bf2f(unsigned short h) {
    return __uint_as_float(((unsigned)h) << 16);
}

// h1s row n = 128 B = 8 chunks of 16 B; logical chunk c stored at c ^ (n&7).
__device__ __forceinline__ void load_row_frag(
    const unsigned char* h1s, int src, int kgrp, short8& r0, short8& r1) {
    unsigned a0 = (unsigned)src * 128u + (((unsigned)(kgrp ^ (src & 7))) << 4);
    r0 = *(const short8*)(h1s + a0);          // feats kgrp*8 .. +8
    r1 = *(const short8*)(h1s + (a0 ^ 64u));  // feats 32+kgrp*8 .. +8
}

// ===== whole network, one block per graph, everything LDS-resident ==========
// LDS map (152832 B):
//   [0,128000)      h1s (bf16 swizzled); during build: xl f[3000]@0, wsum f[1024]@12032
//   [128000)        ends  int[1024]
//   [132096)        dl    float[1024]
//   [136192)        wpart int[64] -> x1b float[64]
//   [136448)        uA (16384): aggv f[3000]@0 / keys u64[1024]@0;
//                   posc i[1024]@12288 -> sred f[1024]@12288;
//                   red f[1024]@8192; a1@12288 a2@12544 z@12672 (tail)
__global__ __launch_bounds__(1024) void k_all(
    const int* __restrict__ ei, const float* __restrict__ ew,
    const float* __restrict__ x,
    const float* __restrict__ w1, const float* __restrict__ b1,
    const float* __restrict__ w2, const float* __restrict__ b2,
    const float* __restrict__ pw,
    const float* __restrict__ l1w, const float* __restrict__ l1b,
    const float* __restrict__ l2w, const float* __restrict__ l2b,
    const float* __restrict__ l3w, const float* __restrict__ l3b,
    unsigned* __restrict__ csr, float* __restrict__ out) {
    __shared__ __align__(16) unsigned char smem[152832];
    unsigned char* h1s = smem;
    unsigned short* h1u = (unsigned short*)smem;
    float* xl   = (float*)smem;                  // build-phase alias
    float* wsum = (float*)(smem + 12032);        // build-phase alias
    int*   ends = (int*)(smem + 128000);
    float* dl   = (float*)(smem + 132096);
    int*   wpart = (int*)(smem + 136192);
    float* x1b   = (float*)(smem + 136192);
    unsigned char* uA = smem + 136448;
    float* aggv = (float*)uA;
    int*   posc = (int*)(uA + 12288);

    int b = blockIdx.x, tid = threadIdx.x;
    int wid = tid >> 6, lane = tid & 63;
    int gbase = b * N_PER, ebase = b * E_PER;

    // ---- phase 0: edges into registers + xl + zero inits ----
    int esrc[EPT], edst[EPT]; float eww[EPT];
    int ne = (tid < (E_PER - (EPT - 1) * 1024)) ? EPT : EPT - 1;
#pragma unroll
    for (int i = 0; i < EPT; i++) {
        if (i < ne) {
            int e = tid + i * 1024;
            esrc[i] = ei[ebase + e] - gbase;
            edst[i] = ei[ETOT + ebase + e] - gbase;
            eww[i]  = ew[ebase + e];
        }
    }
    for (int i = tid; i < N_PER * 3; i += 1024) {
        xl[i] = x[(size_t)gbase * 3 + i];
        aggv[i] = 0.f;
    }
    ends[tid] = 0;
    wsum[tid] = 0.f;
    __syncthreads();
    // ---- phase A: count ----
#pragma unroll
    for (int i = 0; i < EPT; i++)
        if (i < ne) {
            atomicAdd(&ends[edst[i]], 1);
            atomicAdd(&wsum[edst[i]], eww[i]);
        }
    __syncthreads();
    // ---- shuffle inclusive scan of counts; dl ----
    int v = ends[tid];
    int sc = v;
#pragma unroll
    for (int m = 1; m < 64; m <<= 1) {
        int t = __shfl_up(sc, m);
        if (lane >= m) sc += t;
    }
    if (lane == 63) wpart[wid] = sc;
    __syncthreads();
    if (tid < 16) {
        int s2 = wpart[tid];
#pragma unroll
        for (int m = 1; m < 16; m <<= 1) {
            int t = __shfl_up(s2, m);
            if (tid >= m) s2 += t;
        }
        wpart[tid] = s2;
    }
    __syncthreads();
    int incl = sc + (wid > 0 ? wpart[wid - 1] : 0);
    ends[tid] = incl;
    posc[tid] = incl - v;
    dl[tid] = rsqrtf(wsum[tid] + 1.0f);
    __syncthreads();
    // ---- phase B: CSR fill (packed u32) + conv1 scatter + self-term ----
    if (tid < N_PER) {
        float d2 = dl[tid] * dl[tid];
        atomicAdd(&aggv[tid * 3 + 0], d2 * xl[tid * 3 + 0]);
        atomicAdd(&aggv[tid * 3 + 1], d2 * xl[tid * 3 + 1]);
        atomicAdd(&aggv[tid * 3 + 2], d2 * xl[tid * 3 + 2]);
    }
#pragma unroll
    for (int i = 0; i < EPT; i++)
        if (i < ne) {
            float cf = dl[esrc[i]] * eww[i] * dl[edst[i]];
            int p = atomicAdd(&posc[edst[i]], 1);
            csr[ebase + p] = ((unsigned)f2bf(cf) << 16) | (unsigned)esrc[i];
            atomicAdd(&aggv[edst[i] * 3 + 0], cf * xl[esrc[i] * 3 + 0]);
            atomicAdd(&aggv[edst[i] * 3 + 1], cf * xl[esrc[i] * 3 + 1]);
            atomicAdd(&aggv[edst[i] * 3 + 2], cf * xl[esrc[i] * 3 + 2]);
        }
    __syncthreads();
    // ---- W1: h1 = relu(agg @ W1 + b1) -> swizzled LDS (xl/wsum die) ----
    {
        float w0 = w1[lane], w1v = w1[64 + lane], w2v = w1[128 + lane], bf = b1[lane];
        float* sred = (float*)(uA + 12288);      // posc dead
        float px = 0.f;
        for (int node = wid; node < N_PER; node += 16) {
            float a0 = aggv[node * 3], a1 = aggv[node * 3 + 1], a2 = aggv[node * 3 + 2];
            float hv = fmaxf(a0 * w0 + a1 * w1v + a2 * w2v + bf, 0.f);
            h1u[node * 64 + ((((lane >> 3) ^ (node & 7))) << 3) + (lane & 7)] = f2bf(hv);
            px += hv;
        }
        __syncthreads();                         // aggv dead only after all reads
        sred[wid * 64 + lane] = px;
        __syncthreads();
        if (tid < 64) {
            float t = 0.f;
            for (int r = 0; r < 16; r++) t += sred[r * 64 + tid];
            x1b[tid] = t * (1.0f / N_PER);
        }
    }
    // ---- conv2 agg: 4 tiles interleaved (4 independent load chains) ----
    int kgrp = lane >> 4, nloc = lane & 15;
    float acc[4][16];
    int sA[4], cntA[4], mxA[4];
    unsigned pre[4];
    int kmax = 0;
#pragma unroll
    for (int ti = 0; ti < 4; ti++) {
        int t = wid + ti * 16;
        int li = t * 16 + nloc;
        bool valid = li < N_PER;
        if (valid) {
            float d2 = dl[li] * dl[li];
            short8 r0, r1;
            load_row_frag(h1s, li, kgrp, r0, r1);
#pragma unroll
            for (int j = 0; j < 8; j++) {
                acc[ti][j]     = d2 * bf2f((unsigned short)r0[j]);
                acc[ti][8 + j] = d2 * bf2f((unsigned short)r1[j]);
            }
        } else {
#pragma unroll
            for (int j = 0; j < 16; j++) acc[ti][j] = 0.f;
        }
        int s = 0, cnt = 0;
        if (valid) {
            s = (li > 0) ? ends[li - 1] : 0;
            cnt = ends[li] - s;
        }
        int mx = cnt;
#pragma unroll
        for (int m = 1; m < 16; m <<= 1) mx = max(mx, __shfl_xor(mx, m));
        sA[ti] = s; cntA[ti] = cnt; mxA[ti] = mx;
        kmax = max(kmax, mx);
        pre[ti] = csr[min(ebase + s, ETOT - 1)];
    }
    for (int k = 0; k < kmax; k++) {
#pragma unroll
        for (int ti = 0; ti < 4; ti++) {
            if (k < mxA[ti]) {
                unsigned q = pre[ti];
                int nxt = sA[ti] + min(k + 1, max(cntA[ti] - 1, 0));
                pre[ti] = csr[min(ebase + nxt, ETOT - 1)];
                if (k < cntA[ti]) {
                    int src = (int)(q & 0xFFFFu);
                    float cf = __uint_as_float(q & 0xFFFF0000u);
                    short8 r0, r1;
                    load_row_frag(h1s, src, kgrp, r0, r1);
#pragma unroll
                    for (int j = 0; j < 8; j++) {
                        acc[ti][j]     += cf * bf2f((unsigned short)r0[j]);
                        acc[ti][8 + j] += cf * bf2f((unsigned short)r1[j]);
                    }
                }
            }
        }
    }
    short8 AfS[4][2];
#pragma unroll
    for (int ti = 0; ti < 4; ti++) {
        short8 a0, a1;
#pragma unroll
        for (int j = 0; j < 8; j++) {
            a0[j] = (short)f2bf(acc[ti][j]);
            a1[j] = (short)f2bf(acc[ti][8 + j]);
        }
        AfS[ti][0] = a0;
        AfS[ti][1] = a1;
    }
    __syncthreads();   // all agg reads done; h1s may be overwritten with h2
    // ---- W2 via MFMA + epilogue (h2 -> h1s, scores -> keys) ----
    unsigned long long* keys = (unsigned long long*)uA;
    {
        short8 Bf[2][4];
#pragma unroll
        for (int kh = 0; kh < 2; ++kh)
#pragma unroll
            for (int c = 0; c < 4; ++c) {
                short8 t;
#pragma unroll
                for (int j = 0; j < 8; ++j)
                    t[j] = (short)f2bf(w2[(kh * 32 + kgrp * 8 + j) * 64 + c * 16 + nloc]);
                Bf[kh][c] = t;
            }
        float b2c[4], pwc[4];
#pragma unroll
        for (int c = 0; c < 4; ++c) {
            b2c[c] = b2[c * 16 + nloc];
            pwc[c] = pw[c * 16 + nloc];
        }
        float invn;
        {
            float p = pw[lane], pn = p * p;
#pragma unroll
            for (int m = 32; m; m >>= 1) pn += __shfl_xor(pn, m);
            invn = rsqrtf(pn);
        }
        if (tid >= N_PER) keys[tid] = 0ull;      // pad entries sort last
#pragma unroll
        for (int ti = 0; ti < 4; ti++) {
            int t = wid + ti * 16;
            if (t >= 63) continue;
            float4_ accv[4];
#pragma unroll
            for (int c = 0; c < 4; ++c) accv[c] = (float4_){0.f, 0.f, 0.f, 0.f};
#pragma unroll
            for (int kh = 0; kh < 2; ++kh)
#pragma unroll
                for (int c = 0; c < 4; ++c)
                    accv[c] = __builtin_amdgcn_mfma_f32_16x16x32_bf16(AfS[ti][kh], Bf[kh][c], accv[c], 0, 0, 0);
#pragma unroll
            for (int r2 = 0; r2 < 4; ++r2) {
                int li2 = t * 16 + kgrp * 4 + r2;   // C layout: row=(lane>>4)*4+reg
                bool valid2 = li2 < N_PER;
                float sp = 0.f;
#pragma unroll
                for (int c = 0; c < 4; ++c) {
                    float hv = fmaxf(accv[c][r2] + b2c[c], 0.f);
                    sp += hv * pwc[c];
                    if (valid2) {
                        int f = c * 16 + nloc;
                        h1u[li2 * 64 + ((((f >> 3) ^ (li2 & 7))) << 3) + (f & 7)] = f2bf(hv);
                    }
                }
#pragma unroll
                for (int m = 1; m < 16; m <<= 1) sp += __shfl_xor(sp, m);
                if (valid2 && nloc == 0) {
                    float scv = tanhf(sp * invn);
                    unsigned bits = __float_as_uint(scv);
                    unsigned u = (bits & 0x80000000u) ? ~bits : (bits | 0x80000000u);
                    keys[li2] = ((unsigned long long)u << 32) | (unsigned)(1023 - li2);
                }
            }
        }
    }
    __syncthreads();
    // ---- hybrid bitonic sort: j<64 via shfl, j>=64 via LDS ----
    {
        unsigned long long key = keys[tid];
        for (int k = 2; k <= 1024; k <<= 1) {
            for (int j = k >> 1; j > 0; j >>= 1) {
                bool desc = (tid & k) == 0;
                unsigned long long p;
                if (j >= 64) {
                    keys[tid] = key;
                    __syncthreads();
                    p = keys[tid ^ j];
                    __syncthreads();
                } else {
                    p = __shfl_xor(key, j);
                }
                bool low = (tid & j) == 0;
                bool sw = low ? (desc ? (key < p) : (key > p))
                              : (desc ? (p < key) : (p > key));
                if (sw) key = p;
            }
        }
        keys[tid] = key;
    }
    __syncthreads();
    // ---- weighted mean over top-K (h2 from LDS) + MLP ----
    float* red   = (float*)(uA + 8192);
    float* a1buf = (float*)(uA + 12288);
    float* a2buf = (float*)(uA + 12544);
    float* zbuf  = (float*)(uA + 12672);
    {
        int f = tid & 63, w16 = tid >> 6;
        float acc2 = 0.f;
        for (int r = w16; r < KSEL; r += 16) {
            unsigned long long key = keys[r];
            int idx = 1023 - (int)(key & 0xFFFFFFFFu);
            unsigned u = (unsigned)(key >> 32);
            unsigned bits = (u & 0x80000000u) ? (u & 0x7FFFFFFFu) : ~u;
            float val = __uint_as_float(bits);
            acc2 += val * bf2f(h1u[idx * 64 + ((((f >> 3) ^ (idx & 7))) << 3) + (f & 7)]);
        }
        red[tid] = acc2;
    }
    __syncthreads();
    if (tid < 64) {
        float s2 = 0.f;
        for (int ww = 0; ww < 16; ww++) s2 += red[ww * 64 + tid];
        zbuf[tid] = x1b[tid] + s2 * (1.0f / KSEL);
    }
    __syncthreads();
    if (tid < 64) {
        float a = l1b[tid];
        for (int k = 0; k < 64; k++) a += zbuf[k] * l1w[k * 64 + tid];
        a1buf[tid] = fmaxf(a, 0.f);
    }
    __syncthreads();
    if (tid < 32) {
        float a = l2b[tid];
        for (int k = 0; k < 64; k++) a += a1buf[k] * l2w[k * 32 + tid];
        a2buf[tid] = fmaxf(a, 0.f);
    }
    __syncthreads();
    if (tid == 0) {
        float t = l3b[0];
        for (int k = 0; k < 32; k++) t += a2buf[k] * l3w[k];
        out[b] = 1.0f / (1.0f + expf(-t));
    }
}

extern "C" void kernel_launch(void* const* d_in, const int* in_sizes, int n_in,
                              void* d_out, int out_size, void* d_ws, size_t ws_size,
                              hipStream_t stream) {
    const float* x   = (const float*)d_in[0];
    const int*   ei  = (const int*)d_in[1];
    const float* ew  = (const float*)d_in[2];
    const float* c1w = (const float*)d_in[4];
    const float* c1b = (const float*)d_in[5];
    const float* c2w = (const float*)d_in[6];
    const float* c2b = (const float*)d_in[7];
    const float* pw  = (const float*)d_in[8];
    const float* l1w = (const float*)d_in[9];
    const float* l1b = (const float*)d_in[10];
    const float* l2w = (const float*)d_in[11];
    const float* l2b = (const float*)d_in[12];
    const float* l3w = (const float*)d_in[13];
    const float* l3b = (const float*)d_in[14];
    float* out = (float*)d_out;
    unsigned* csr = (unsigned*)d_ws;
    (void)ws_size; (void)in_sizes; (void)n_in; (void)out_size;

    k_all<<<B_G, 1024, 0, stream>>>(ei, ew, x, c1w, c1b, c2w, c2b, pw,
                                    l1w, l1b, l2w, l2b, l3w, l3b, csr, out);
}

// Round 8
// 192.341 us; speedup vs baseline: 1.2241x; 1.2241x over previous
//
#include <hip/hip_runtime.h>

#define B_G   100
#define N_PER 1000
#define E_PER 12000
#define NTOT  (B_G * N_PER)
#define ETOT  (B_G * E_PER)
#define KSEL  800
#define EPT   12
#define CAP   48            // fixed CSR stride; Poisson(12) max over 1e5 ~ 38

typedef __attribute__((ext_vector_type(8))) short short8;
typedef __attribute__((ext_vector_type(4))) float float4_;

__device__ __forceinline__ unsigned short f2bf(float f) {
    unsigned u = __float_as_uint(f);
    u += 0x7fffu + ((u >> 16) & 1u);          // RNE
    return (unsigned short)(u >> 16);
}
__device__ __forceinline__ float bf2f(unsigned short h) {
    return __uint_as_float(((unsigned)h) << 16);
}
__device__ __forceinline__ float upk(unsigned q) {          // bf16 ew in hi16
    return __uint_as_float(q & 0xFFFF0000u);
}

// z rows: row n = 128 B = 8 chunks of 16 B; logical chunk c stored at c ^ (n&7).
__device__ __forceinline__ void load_row_frag(
    const unsigned char* h1s, int src, int kgrp, short8& r0, short8& r1) {
    unsigned a0 = (unsigned)src * 128u + (((unsigned)(kgrp ^ (src & 7))) << 4);
    r0 = *(const short8*)(h1s + a0);          // feats kgrp*8 .. +8
    r1 = *(const short8*)(h1s + (a0 ^ 64u));  // feats 32+kgrp*8 .. +8
}

// ===== whole network, one block per graph ===================================
// LDS (152832 B): [0,128000) h1s = z/h2 bf16 swizzled; during build xl/y f[3000]
//   cnt i[1024]@128000  dl f[1024]@132096  x1b f[64]@136192
//   uA@136448 (16384): aggv f[3000] / keys u64[1024]; sred f[1024]@12288;
//   red f[1024]@8192; a1@12288 a2@12544 z@12672
__global__ __launch_bounds__(1024) void k_all(
    const int* __restrict__ ei, const float* __restrict__ ew,
    const float* __restrict__ x,
    const float* __restrict__ w1, const float* __restrict__ b1,
    const float* __restrict__ w2, const float* __restrict__ b2,
    const float* __restrict__ pw,
    const float* __restrict__ l1w, const float* __restrict__ l1b,
    const float* __restrict__ l2w, const float* __restrict__ l2b,
    const float* __restrict__ l3w, const float* __restrict__ l3b,
    unsigned* __restrict__ csr, float* __restrict__ out) {
    __shared__ __align__(16) unsigned char smem[152832];
    unsigned char* h1s = smem;
    unsigned short* h1u = (unsigned short*)smem;
    float* xl   = (float*)smem;                  // build-phase alias (y in place)
    int*   cnt  = (int*)(smem + 128000);
    float* dl   = (float*)(smem + 132096);
    float* x1b  = (float*)(smem + 136192);
    unsigned char* uA = smem + 136448;
    float* aggv = (float*)uA;

    int b = blockIdx.x, tid = threadIdx.x;
    int wid = tid >> 6, lane = tid & 63;
    int gbase = b * N_PER, ebase = b * E_PER;
    unsigned* csrg = csr + (size_t)b * N_PER * CAP;

    // ---- init ----
    cnt[tid] = 0;
    for (int i = tid; i < N_PER * 3; i += 1024) xl[i] = x[(size_t)gbase * 3 + i];
    __syncthreads();
    // ---- fill: ONE pass over edges; 1 LDS atomic + 1 global store per edge --
#pragma unroll
    for (int i = 0; i < EPT; i++) {
        int e = tid + i * 1024;
        if (e < E_PER) {
            int src = ei[ebase + e] - gbase;
            int dst = ei[ETOT + ebase + e] - gbase;
            float w = ew[ebase + e];
            int p = atomicAdd(&cnt[dst], 1);
            if (p < CAP) csrg[dst * CAP + p] = ((unsigned)f2bf(w) << 16) | (unsigned)src;
        }
    }
    __syncthreads();
    // ---- wsum gather (L2-hot csr) -> dl; then y = dl*x in place ----
    if (tid < N_PER) {
        int c = min(cnt[tid], CAP);
        const unsigned* row = csrg + tid * CAP;
        float s0 = 0.f, s1 = 0.f, s2 = 0.f, s3 = 0.f;
        int k = 0;
        for (; k + 4 <= c; k += 4) {
            unsigned q0 = row[k], q1 = row[k + 1], q2 = row[k + 2], q3 = row[k + 3];
            s0 += upk(q0); s1 += upk(q1); s2 += upk(q2); s3 += upk(q3);
        }
        for (; k < c; k++) s0 += upk(row[k]);
        dl[tid] = rsqrtf((s0 + s1) + (s2 + s3) + 1.0f);
    }
    __syncthreads();
    if (tid < N_PER) {
        float d = dl[tid];
        xl[tid * 3 + 0] *= d;
        xl[tid * 3 + 1] *= d;
        xl[tid * 3 + 2] *= d;
    }
    __syncthreads();
    // ---- conv1 gather: agg = dl[dst]*(y[dst] + sum ew*y[src]) ----
    if (tid < N_PER) {
        int c = min(cnt[tid], CAP);
        const unsigned* row = csrg + tid * CAP;
        float a0 = xl[tid * 3 + 0], a1 = xl[tid * 3 + 1], a2 = xl[tid * 3 + 2];
        int k = 0;
        for (; k + 4 <= c; k += 4) {
            unsigned q0 = row[k], q1 = row[k + 1], q2 = row[k + 2], q3 = row[k + 3];
            int i0 = (q0 & 0xFFFFu) * 3, i1 = (q1 & 0xFFFFu) * 3;
            int i2 = (q2 & 0xFFFFu) * 3, i3 = (q3 & 0xFFFFu) * 3;
            float w0 = upk(q0), w1v = upk(q1), w2v = upk(q2), w3 = upk(q3);
            a0 += w0 * xl[i0] + w1v * xl[i1] + w2v * xl[i2] + w3 * xl[i3];
            a1 += w0 * xl[i0 + 1] + w1v * xl[i1 + 1] + w2v * xl[i2 + 1] + w3 * xl[i3 + 1];
            a2 += w0 * xl[i0 + 2] + w1v * xl[i1 + 2] + w2v * xl[i2 + 2] + w3 * xl[i3 + 2];
        }
        for (; k < c; k++) {
            unsigned q = row[k];
            int i0 = (q & 0xFFFFu) * 3;
            float wv = upk(q);
            a0 += wv * xl[i0]; a1 += wv * xl[i0 + 1]; a2 += wv * xl[i0 + 2];
        }
        float d = dl[tid];
        aggv[tid * 3 + 0] = d * a0;
        aggv[tid * 3 + 1] = d * a1;
        aggv[tid * 3 + 2] = d * a2;
    }
    __syncthreads();
    // ---- W1: h1 = relu(agg@W1+b1); store z = dl*h1 swizzled; x1 partials ----
    {
        float w0 = w1[lane], w1v = w1[64 + lane], w2v = w1[128 + lane], bf = b1[lane];
        float* sred = (float*)(uA + 12288);      // no overlap with aggv (12000 B)
        float px = 0.f;
        for (int node = wid; node < N_PER; node += 16) {
            float a0 = aggv[node * 3], a1 = aggv[node * 3 + 1], a2 = aggv[node * 3 + 2];
            float hv = fmaxf(a0 * w0 + a1 * w1v + a2 * w2v + bf, 0.f);
            px += hv;
            float zv = dl[node] * hv;
            h1u[node * 64 + ((((lane >> 3) ^ (node & 7))) << 3) + (lane & 7)] = f2bf(zv);
        }
        sred[wid * 64 + lane] = px;
        __syncthreads();
        if (tid < 64) {
            float t = 0.f;
            for (int r = 0; r < 16; r++) t += sred[r * 64 + tid];
            x1b[tid] = t * (1.0f / N_PER);
        }
    }
    __syncthreads();
    // ---- conv2 agg in A-frag layout: g = dl*(z[self] + sum ew*z[src]) ----
    int kgrp = lane >> 4, nloc = lane & 15;
    short8 AfS[4][2];
#pragma unroll
    for (int ti = 0; ti < 4; ti++) {
        int t = wid + ti * 16;
        int li = t * 16 + nloc;
        bool valid = li < N_PER;
        float acc[16];
        int cn = 0, base = 0;
        if (valid) {
            short8 r0, r1;
            load_row_frag(h1s, li, kgrp, r0, r1);
#pragma unroll
            for (int j = 0; j < 8; j++) {
                acc[j]     = bf2f((unsigned short)r0[j]);
                acc[8 + j] = bf2f((unsigned short)r1[j]);
            }
            cn = min(cnt[li], CAP);
            base = li * CAP;
        } else {
#pragma unroll
            for (int j = 0; j < 16; j++) acc[j] = 0.f;
        }
        int mx = cn;
#pragma unroll
        for (int m = 1; m < 16; m <<= 1) mx = max(mx, __shfl_xor(mx, m));
        int cl = max(cn - 1, 0);
        unsigned q = csrg[base];
        for (int k = 0; k < mx; k++) {
            unsigned qn = csrg[base + min(k + 1, cl)];     // 1-deep prefetch
            if (k < cn) {
                int src = (int)(q & 0xFFFFu);
                float wv = upk(q);
                short8 r0, r1;
                load_row_frag(h1s, src, kgrp, r0, r1);
#pragma unroll
                for (int j = 0; j < 8; j++) {
                    acc[j]     += wv * bf2f((unsigned short)r0[j]);
                    acc[8 + j] += wv * bf2f((unsigned short)r1[j]);
                }
            }
            q = qn;
        }
        float dv = valid ? dl[li] : 0.f;
        short8 a0, a1;
#pragma unroll
        for (int j = 0; j < 8; j++) {
            a0[j] = (short)f2bf(dv * acc[j]);
            a1[j] = (short)f2bf(dv * acc[8 + j]);
        }
        AfS[ti][0] = a0;
        AfS[ti][1] = a1;
    }
    __syncthreads();   // all agg reads done; h1s may be overwritten with h2
    // ---- W2 via MFMA + epilogue (h2 -> h1s, scores -> keys) ----
    unsigned long long* keys = (unsigned long long*)uA;
    {
        short8 Bf[2][4];
#pragma unroll
        for (int kh = 0; kh < 2; ++kh)
#pragma unroll
            for (int c = 0; c < 4; ++c) {
                short8 t;
#pragma unroll
                for (int j = 0; j < 8; ++j)
                    t[j] = (short)f2bf(w2[(kh * 32 + kgrp * 8 + j) * 64 + c * 16 + nloc]);
                Bf[kh][c] = t;
            }
        float b2c[4], pwc[4];
#pragma unroll
        for (int c = 0; c < 4; ++c) {
            b2c[c] = b2[c * 16 + nloc];
            pwc[c] = pw[c * 16 + nloc];
        }
        float invn;
        {
            float p = pw[lane], pn = p * p;
#pragma unroll
            for (int m = 32; m; m >>= 1) pn += __shfl_xor(pn, m);
            invn = rsqrtf(pn);
        }
        if (tid >= N_PER) keys[tid] = 0ull;      // pad entries sort last
#pragma unroll
        for (int ti = 0; ti < 4; ti++) {
            int t = wid + ti * 16;
            if (t >= 63) continue;
            float4_ accv[4];
#pragma unroll
            for (int c = 0; c < 4; ++c) accv[c] = (float4_){0.f, 0.f, 0.f, 0.f};
#pragma unroll
            for (int kh = 0; kh < 2; ++kh)
#pragma unroll
                for (int c = 0; c < 4; ++c)
                    accv[c] = __builtin_amdgcn_mfma_f32_16x16x32_bf16(AfS[ti][kh], Bf[kh][c], accv[c], 0, 0, 0);
#pragma unroll
            for (int r2 = 0; r2 < 4; ++r2) {
                int li2 = t * 16 + kgrp * 4 + r2;   // C layout: row=(lane>>4)*4+reg
                bool valid2 = li2 < N_PER;
                float sp = 0.f;
#pragma unroll
                for (int c = 0; c < 4; ++c) {
                    float hv = fmaxf(accv[c][r2] + b2c[c], 0.f);
                    sp += hv * pwc[c];
                    if (valid2) {
                        int f = c * 16 + nloc;
                        h1u[li2 * 64 + ((((f >> 3) ^ (li2 & 7))) << 3) + (f & 7)] = f2bf(hv);
                    }
                }
#pragma unroll
                for (int m = 1; m < 16; m <<= 1) sp += __shfl_xor(sp, m);
                if (valid2 && nloc == 0) {
                    float scv = tanhf(sp * invn);
                    unsigned bits = __float_as_uint(scv);
                    unsigned u = (bits & 0x80000000u) ? ~bits : (bits | 0x80000000u);
                    keys[li2] = ((unsigned long long)u << 32) | (unsigned)(1023 - li2);
                }
            }
        }
    }
    __syncthreads();
    // ---- hybrid bitonic sort: j<64 via shfl, j>=64 via LDS ----
    {
        unsigned long long key = keys[tid];
        for (int k = 2; k <= 1024; k <<= 1) {
            for (int j = k >> 1; j > 0; j >>= 1) {
                bool desc = (tid & k) == 0;
                unsigned long long p;
                if (j >= 64) {
                    keys[tid] = key;
                    __syncthreads();
                    p = keys[tid ^ j];
                    __syncthreads();
                } else {
                    p = __shfl_xor(key, j);
                }
                bool low = (tid & j) == 0;
                bool sw = low ? (desc ? (key < p) : (key > p))
                              : (desc ? (p < key) : (p > key));
                if (sw) key = p;
            }
        }
        keys[tid] = key;
    }
    __syncthreads();
    // ---- weighted mean over top-K (h2 from LDS) + MLP ----
    float* red   = (float*)(uA + 8192);
    float* a1buf = (float*)(uA + 12288);
    float* a2buf = (float*)(uA + 12544);
    float* zbuf  = (float*)(uA + 12672);
    {
        int f = tid & 63, w16 = tid >> 6;
        float acc2 = 0.f;
        for (int r = w16; r < KSEL; r += 16) {
            unsigned long long key = keys[r];
            int idx = 1023 - (int)(key & 0xFFFFFFFFu);
            unsigned u = (unsigned)(key >> 32);
            unsigned bits = (u & 0x80000000u) ? (u & 0x7FFFFFFFu) : ~u;
            float val = __uint_as_float(bits);
            acc2 += val * bf2f(h1u[idx * 64 + ((((f >> 3) ^ (idx & 7))) << 3) + (f & 7)]);
        }
        red[tid] = acc2;
    }
    __syncthreads();
    if (tid < 64) {
        float s2 = 0.f;
        for (int ww = 0; ww < 16; ww++) s2 += red[ww * 64 + tid];
        zbuf[tid] = x1b[tid] + s2 * (1.0f / KSEL);
    }
    __syncthreads();
    if (tid < 64) {
        float a = l1b[tid];
        for (int k = 0; k < 64; k++) a += zbuf[k] * l1w[k * 64 + tid];
        a1buf[tid] = fmaxf(a, 0.f);
    }
    __syncthreads();
    if (tid < 32) {
        float a = l2b[tid];
        for (int k = 0; k < 64; k++) a += a1buf[k] * l2w[k * 32 + tid];
        a2buf[tid] = fmaxf(a, 0.f);
    }
    __syncthreads();
    if (tid == 0) {
        float t = l3b[0];
        for (int k = 0; k < 32; k++) t += a2buf[k] * l3w[k];
        out[b] = 1.0f / (1.0f + expf(-t));
    }
}

extern "C" void kernel_launch(void* const* d_in, const int* in_sizes, int n_in,
                              void* d_out, int out_size, void* d_ws, size_t ws_size,
                              hipStream_t stream) {
    const float* x   = (const float*)d_in[0];
    const int*   ei  = (const int*)d_in[1];
    const float* ew  = (const float*)d_in[2];
    const float* c1w = (const float*)d_in[4];
    const float* c1b = (const float*)d_in[5];
    const float* c2w = (const float*)d_in[6];
    const float* c2b = (const float*)d_in[7];
    const float* pw  = (const float*)d_in[8];
    const float* l1w = (const float*)d_in[9];
    const float* l1b = (const float*)d_in[10];
    const float* l2w = (const float*)d_in[11];
    const float* l2b = (const float*)d_in[12];
    const float* l3w = (const float*)d_in[13];
    const float* l3b = (const float*)d_in[14];
    float* out = (float*)d_out;
    unsigned* csr = (unsigned*)d_ws;
    (void)ws_size; (void)in_sizes; (void)n_in; (void)out_size;

    k_all<<<B_G, 1024, 0, stream>>>(ei, ew, x, c1w, c1b, c2w, c2b, pw,
                                    l1w, l1b, l2w, l2b, l3w, l3b, csr, out);
}

// Round 9
// 180.971 us; speedup vs baseline: 1.3010x; 1.0628x over previous
//
#include <hip/hip_runtime.h>

#define B_G   100
#define N_PER 1000
#define E_PER 12000
#define NTOT  (B_G * N_PER)
#define ETOT  (B_G * E_PER)
#define KSEL  800
#define EPT   12

typedef __attribute__((ext_vector_type(8))) short short8;
typedef __attribute__((ext_vector_type(4))) float float4_;

__device__ __forceinline__ unsigned short f2bf(float f) {
    unsigned u = __float_as_uint(f);
    u += 0x7fffu + ((u >> 16) & 1u);          // RNE
    return (unsigned short)(u >> 16);
}
__device__ __forceinline__ float upk(unsigned q) {          // bf16 ew in hi16
    return __uint_as_float(q & 0xFFFF0000u);
}
// fp8 e4m3 (z>=0): raw decode = true_value * 2^-120 (exact, incl subnormals)
__device__ __forceinline__ float dec_raw(unsigned byte7f) { // pass (b&0x7f)
    return __uint_as_float(byte7f << 20);
}
__device__ __forceinline__ unsigned enc_fp8(float z) {      // z >= 0, z < 448
    unsigned u = __float_as_uint(z * 0x1p-120f);
    u += 0x7FFFFu + ((u >> 20) & 1u);                       // RNE at bit 20
    return u >> 20;
}

// ===== whole network, one block per graph, EVERYTHING (incl CSR) in LDS =====
// LDS map (136832 B):
//  [0,64000)    zs: fp8 z rows (64 B, chunk-swizzled); xl f[3000] early; h2 linear late
//  [64000)      csr u32[12000]  (bf16 ew <<16 | src)
//  [112000)     ends int[1024]  (inclusive rowptr)
//  [116096)     dl f[1024]      (aliases posc during fill)
//  [120192)     wpart i[16] / x1b f[64]
//  [120448)     uA 16384: aggv f[3000] / keys u64[1024]; sred@12288;
//               red@8192; a1@12288 a2@12544 zb@12672
__global__ __launch_bounds__(1024) void k_all(
    const int* __restrict__ ei, const float* __restrict__ ew,
    const float* __restrict__ x,
    const float* __restrict__ w1, const float* __restrict__ b1,
    const float* __restrict__ w2, const float* __restrict__ b2,
    const float* __restrict__ pw,
    const float* __restrict__ l1w, const float* __restrict__ l1b,
    const float* __restrict__ l2w, const float* __restrict__ l2b,
    const float* __restrict__ l3w, const float* __restrict__ l3b,
    float* __restrict__ out) {
    __shared__ __align__(16) unsigned char smem[136832];
    unsigned char* zs = smem;
    float* xl = (float*)smem;
    unsigned* csr = (unsigned*)(smem + 64000);
    int*   ends = (int*)(smem + 112000);
    float* dl   = (float*)(smem + 116096);
    int*   posc = (int*)(smem + 116096);         // alias, dead before dl
    int*   wpart = (int*)(smem + 120192);
    float* x1b   = (float*)(smem + 120192);
    unsigned char* uA = smem + 120448;
    float* aggv = (float*)uA;

    int b = blockIdx.x, tid = threadIdx.x;
    int wid = tid >> 6, lane = tid & 63;
    int gbase = b * N_PER, ebase = b * E_PER;

    // ---- phase 0: edges into regs (read once), xl load, init ----
    int esrc[EPT], edst[EPT]; float eww[EPT];
    int ne = (tid < (E_PER - (EPT - 1) * 1024)) ? EPT : EPT - 1;
#pragma unroll
    for (int i = 0; i < EPT; i++) {
        if (i < ne) {
            int e = tid + i * 1024;
            esrc[i] = ei[ebase + e] - gbase;
            edst[i] = ei[ETOT + ebase + e] - gbase;
            eww[i]  = ew[ebase + e];
        }
    }
    ends[tid] = 0;
    for (int i = tid; i < N_PER * 3; i += 1024) xl[i] = x[(size_t)gbase * 3 + i];
    __syncthreads();
    // ---- count ----
#pragma unroll
    for (int i = 0; i < EPT; i++)
        if (i < ne) atomicAdd(&ends[edst[i]], 1);
    __syncthreads();
    // ---- shuffle inclusive scan ----
    int v = ends[tid];
    int sc = v;
#pragma unroll
    for (int m = 1; m < 64; m <<= 1) {
        int t = __shfl_up(sc, m);
        if (lane >= m) sc += t;
    }
    if (lane == 63) wpart[wid] = sc;
    __syncthreads();
    if (tid < 16) {
        int s2 = wpart[tid];
#pragma unroll
        for (int m = 1; m < 16; m <<= 1) {
            int t = __shfl_up(s2, m);
            if (tid >= m) s2 += t;
        }
        wpart[tid] = s2;
    }
    __syncthreads();
    int incl = sc + (wid > 0 ? wpart[wid - 1] : 0);
    ends[tid] = incl;
    posc[tid] = incl - v;
    __syncthreads();
    // ---- CSR fill into LDS ----
#pragma unroll
    for (int i = 0; i < EPT; i++)
        if (i < ne) {
            int p = atomicAdd(&posc[edst[i]], 1);
            csr[p] = ((unsigned)f2bf(eww[i]) << 16) | (unsigned)esrc[i];
        }
    __syncthreads();
    // ---- wsum (LDS csr) -> dl; y = dl*x in place ----
    float dmy = 0.f;
    int s0i = 0, e0i = 0;
    if (tid < N_PER) {
        s0i = tid ? ends[tid - 1] : 0;
        e0i = ends[tid];
        float s0 = 0.f, s1 = 0.f;
        int k = s0i;
        for (; k + 2 <= e0i; k += 2) { s0 += upk(csr[k]); s1 += upk(csr[k + 1]); }
        if (k < e0i) s0 += upk(csr[k]);
        dmy = rsqrtf(s0 + s1 + 1.0f);
        dl[tid] = dmy;                            // posc dead (fill barrier above)
        xl[tid * 3 + 0] *= dmy;
        xl[tid * 3 + 1] *= dmy;
        xl[tid * 3 + 2] *= dmy;
    }
    __syncthreads();
    // ---- conv1 gather: agg = dl[dst]*(y[dst] + sum ew*y[src]) ----
    if (tid < N_PER) {
        float a0 = xl[tid * 3 + 0], a1 = xl[tid * 3 + 1], a2 = xl[tid * 3 + 2];
        for (int k = s0i; k < e0i; k++) {
            unsigned q = csr[k];
            int i0 = (int)(q & 0xFFFFu) * 3;
            float wv = upk(q);
            a0 += wv * xl[i0]; a1 += wv * xl[i0 + 1]; a2 += wv * xl[i0 + 2];
        }
        aggv[tid * 3 + 0] = dmy * a0;
        aggv[tid * 3 + 1] = dmy * a1;
        aggv[tid * 3 + 2] = dmy * a2;
    }
    __syncthreads();
    // ---- W1: h1 = relu(agg@W1+b1); z = dl*h1 -> fp8 swizzled; x1 partials ---
    {
        float w0 = w1[lane], w1v = w1[64 + lane], w2v = w1[128 + lane], bf = b1[lane];
        float* sred = (float*)(uA + 12288);
        float px = 0.f;
        int chunk = (lane & 31) >> 3;
        int word  = ((lane >= 32) ? 2 : 0) + ((lane & 7) >> 2);
        for (int node = wid; node < N_PER; node += 16) {
            float a0 = aggv[node * 3], a1 = aggv[node * 3 + 1], a2 = aggv[node * 3 + 2];
            float hv = fmaxf(a0 * w0 + a1 * w1v + a2 * w2v + bf, 0.f);
            px += hv;
            unsigned byte = enc_fp8(dl[node] * hv);
            unsigned t1 = __shfl_xor(byte, 1);
            unsigned v16 = (lane & 1) ? (t1 | (byte << 8)) : (byte | (t1 << 8));
            unsigned t2 = __shfl_xor(v16, 2);
            unsigned v32 = (lane & 2) ? (t2 | (v16 << 16)) : (v16 | (t2 << 16));
            if ((lane & 3) == 0) {
                int cs = chunk ^ ((node >> 1) & 3);
                *(unsigned*)(zs + node * 64 + cs * 16 + word * 4) = v32;
            }
        }
        sred[wid * 64 + lane] = px;
        __syncthreads();
        if (tid < 64) {
            float t = 0.f;
            for (int r = 0; r < 16; r++) t += sred[r * 64 + tid];
            x1b[tid] = t * (1.0f / N_PER);
        }
    }
    // (zs complete at sred barrier; conv2 may proceed)
    // ---- conv2 agg in A-frag layout: g = dl*(z_self + sum ew*z_src) --------
    int kgrp = lane >> 4, nloc = lane & 15;
    short8 AfS[4][2];
#pragma unroll
    for (int ti = 0; ti < 4; ti++) {
        int t = wid + ti * 16;
        int li = t * 16 + nloc;
        bool valid = li < N_PER;
        float acc[16];
        int s = 0, cn = 0;
        if (valid) {
            uint4 rv = *(const uint4*)(zs + li * 64 + ((kgrp ^ ((li >> 1) & 3)) << 4));
#pragma unroll
            for (int j = 0; j < 4; j++) {
                acc[j]      = dec_raw((rv.x >> (8 * j)) & 0x7Fu);
                acc[4 + j]  = dec_raw((rv.y >> (8 * j)) & 0x7Fu);
                acc[8 + j]  = dec_raw((rv.z >> (8 * j)) & 0x7Fu);
                acc[12 + j] = dec_raw((rv.w >> (8 * j)) & 0x7Fu);
            }
            s = li ? ends[li - 1] : 0;
            cn = ends[li] - s;
        } else {
#pragma unroll
            for (int j = 0; j < 16; j++) acc[j] = 0.f;
        }
        int mx = cn;
#pragma unroll
        for (int m = 1; m < 16; m <<= 1) mx = max(mx, __shfl_xor(mx, m));
        for (int k = 0; k < mx; k++) {
            if (k < cn) {
                unsigned q = csr[s + k];
                int src = (int)(q & 0xFFFFu);
                float wv = upk(q);
                uint4 rv = *(const uint4*)(zs + src * 64 + ((kgrp ^ ((src >> 1) & 3)) << 4));
#pragma unroll
                for (int j = 0; j < 4; j++) {
                    acc[j]      += wv * dec_raw((rv.x >> (8 * j)) & 0x7Fu);
                    acc[4 + j]  += wv * dec_raw((rv.y >> (8 * j)) & 0x7Fu);
                    acc[8 + j]  += wv * dec_raw((rv.z >> (8 * j)) & 0x7Fu);
                    acc[12 + j] += wv * dec_raw((rv.w >> (8 * j)) & 0x7Fu);
                }
            }
        }
        float scale = (valid ? dl[li] : 0.f) * 0x1p120f;
        short8 a0, a1;
#pragma unroll
        for (int j = 0; j < 8; j++) {
            a0[j] = (short)f2bf(scale * acc[j]);      // feats kgrp*8+j
            a1[j] = (short)f2bf(scale * acc[8 + j]);  // feats 32+kgrp*8+j
        }
        AfS[ti][0] = a0;
        AfS[ti][1] = a1;
    }
    __syncthreads();   // all z reads done; zs may be overwritten with h2
    // ---- W2 via MFMA + epilogue (h2 fp8 linear -> zs, scores -> keys) ------
    unsigned long long* keys = (unsigned long long*)uA;
    {
        short8 Bf[2][4];
#pragma unroll
        for (int kh = 0; kh < 2; ++kh)
#pragma unroll
            for (int c = 0; c < 4; ++c) {
                short8 t;
#pragma unroll
                for (int j = 0; j < 8; ++j)
                    t[j] = (short)f2bf(w2[(kh * 32 + kgrp * 8 + j) * 64 + c * 16 + nloc]);
                Bf[kh][c] = t;
            }
        float b2c[4], pwc[4];
#pragma unroll
        for (int c = 0; c < 4; ++c) {
            b2c[c] = b2[c * 16 + nloc];
            pwc[c] = pw[c * 16 + nloc];
        }
        float invn;
        {
            float p = pw[lane], pn = p * p;
#pragma unroll
            for (int m = 32; m; m >>= 1) pn += __shfl_xor(pn, m);
            invn = rsqrtf(pn);
        }
        if (tid >= N_PER) keys[tid] = 0ull;      // pad entries sort last
#pragma unroll
        for (int ti = 0; ti < 4; ti++) {
            int t = wid + ti * 16;
            if (t >= 63) continue;
            float4_ accv[4];
#pragma unroll
            for (int c = 0; c < 4; ++c) accv[c] = (float4_){0.f, 0.f, 0.f, 0.f};
#pragma unroll
            for (int kh = 0; kh < 2; ++kh)
#pragma unroll
                for (int c = 0; c < 4; ++c)
                    accv[c] = __builtin_amdgcn_mfma_f32_16x16x32_bf16(AfS[ti][kh], Bf[kh][c], accv[c], 0, 0, 0);
#pragma unroll
            for (int r2 = 0; r2 < 4; ++r2) {
                int li2 = t * 16 + kgrp * 4 + r2;   // C layout: row=(lane>>4)*4+reg
                bool valid2 = li2 < N_PER;
                float sp = 0.f;
#pragma unroll
                for (int c = 0; c < 4; ++c) {
                    float hv = fmaxf(accv[c][r2] + b2c[c], 0.f);
                    sp += hv * pwc[c];
                    if (valid2) zs[li2 * 64 + c * 16 + nloc] = (unsigned char)enc_fp8(hv);
                }
#pragma unroll
                for (int m = 1; m < 16; m <<= 1) sp += __shfl_xor(sp, m);
                if (valid2 && nloc == 0) {
                    float scv = tanhf(sp * invn);
                    unsigned bits = __float_as_uint(scv);
                    unsigned u = (bits & 0x80000000u) ? ~bits : (bits | 0x80000000u);
                    keys[li2] = ((unsigned long long)u << 32) | (unsigned)(1023 - li2);
                }
            }
        }
    }
    __syncthreads();
    // ---- hybrid bitonic sort: j<64 via shfl, j>=64 via LDS ----
    {
        unsigned long long key = keys[tid];
        for (int k = 2; k <= 1024; k <<= 1) {
            for (int j = k >> 1; j > 0; j >>= 1) {
                bool desc = (tid & k) == 0;
                unsigned long long p;
                if (j >= 64) {
                    keys[tid] = key;
                    __syncthreads();
                    p = keys[tid ^ j];
                    __syncthreads();
                } else {
                    p = __shfl_xor(key, j);
                }
                bool low = (tid & j) == 0;
                bool sw = low ? (desc ? (key < p) : (key > p))
                              : (desc ? (p < key) : (p > key));
                if (sw) key = p;
            }
        }
        keys[tid] = key;
    }
    __syncthreads();
    // ---- weighted mean over top-K (h2 fp8 from LDS) + MLP ----
    float* red   = (float*)(uA + 8192);
    float* a1buf = (float*)(uA + 12288);
    float* a2buf = (float*)(uA + 12544);
    float* zbuf  = (float*)(uA + 12672);
    {
        int f = tid & 63, w16 = tid >> 6;
        float acc2 = 0.f;
        for (int r = w16; r < KSEL; r += 16) {
            unsigned long long key = keys[r];
            int idx = 1023 - (int)(key & 0xFFFFFFFFu);
            unsigned u = (unsigned)(key >> 32);
            unsigned bits = (u & 0x80000000u) ? (u & 0x7FFFFFFFu) : ~u;
            float valS = __uint_as_float(bits) * 0x1p120f;
            acc2 += valS * dec_raw((unsigned)zs[idx * 64 + f] & 0x7Fu);
        }
        red[tid] = acc2;
    }
    __syncthreads();
    if (tid < 64) {
        float s2 = 0.f;
        for (int ww = 0; ww < 16; ww++) s2 += red[ww * 64 + tid];
        zbuf[tid] = x1b[tid] + s2 * (1.0f / KSEL);
    }
    __syncthreads();
    if (tid < 64) {
        float a = l1b[tid];
        for (int k = 0; k < 64; k++) a += zbuf[k] * l1w[k * 64 + tid];
        a1buf[tid] = fmaxf(a, 0.f);
    }
    __syncthreads();
    if (tid < 32) {
        float a = l2b[tid];
        for (int k = 0; k < 64; k++) a += a1buf[k] * l2w[k * 32 + tid];
        a2buf[tid] = fmaxf(a, 0.f);
    }
    __syncthreads();
    if (tid == 0) {
        float t = l3b[0];
        for (int k = 0; k < 32; k++) t += a2buf[k] * l3w[k];
        out[b] = 1.0f / (1.0f + expf(-t));
    }
}

extern "C" void kernel_launch(void* const* d_in, const int* in_sizes, int n_in,
                              void* d_out, int out_size, void* d_ws, size_t ws_size,
                              hipStream_t stream) {
    const float* x   = (const float*)d_in[0];
    const int*   ei  = (const int*)d_in[1];
    const float* ew  = (const float*)d_in[2];
    const float* c1w = (const float*)d_in[4];
    const float* c1b = (const float*)d_in[5];
    const float* c2w = (const float*)d_in[6];
    const float* c2b = (const float*)d_in[7];
    const float* pw  = (const float*)d_in[8];
    const float* l1w = (const float*)d_in[9];
    const float* l1b = (const float*)d_in[10];
    const float* l2w = (const float*)d_in[11];
    const float* l2b = (const float*)d_in[12];
    const float* l3w = (const float*)d_in[13];
    const float* l3b = (const float*)d_in[14];
    float* out = (float*)d_out;
    (void)d_ws; (void)ws_size; (void)in_sizes; (void)n_in; (void)out_size;

    k_all<<<B_G, 1024, 0, stream>>>(ei, ew, x, c1w, c1b, c2w, c2b, pw,
                                    l1w, l1b, l2w, l2b, l3w, l3b, out);
}